// Round 1
// baseline (307.223 us; speedup 1.0000x reference)
//
#include <hip/hip_runtime.h>

// NeRF volume render: B rays x S=64 samples, one 64-lane wave per ray.
// alpha_i = 1 - exp(-sigma_i)
// T_i = prod_{j<i} (1 - alpha_j + 1e-10)   (exclusive cumprod, wave scan)
// w_i = alpha_i * T_i
// rgb_map = sum_i w_i * rgb_i ; depth_map = sum_i w_i * t_i, t = linspace(2,6,64)

#define NSAMP 64
#define WAVES_PER_BLOCK 4

__global__ __launch_bounds__(256) void nerf_render_kernel(
    const float* __restrict__ rgb,     // [B, 64, 3]
    const float* __restrict__ sigma,   // [B, 64]
    float* __restrict__ rgb_map,       // [B, 3]
    float* __restrict__ depth_map,     // [B]
    int n_rays)
{
    const int lane = threadIdx.x & 63;
    const int wave = threadIdx.x >> 6;
    const int ray  = blockIdx.x * WAVES_PER_BLOCK + wave;
    if (ray >= n_rays) return;

    // Coalesced loads: lane j handles sample j of this ray.
    const float sg = sigma[(size_t)ray * NSAMP + lane];
    const float* rp = rgb + ((size_t)ray * NSAMP + lane) * 3;
    const float r = rp[0];
    const float g = rp[1];
    const float b = rp[2];

    const float alpha = 1.0f - expf(-sg);
    const float v = 1.0f - alpha + 1e-10f;   // in (1e-10, 1]

    // Inclusive multiplicative Hillis-Steele scan across the 64-lane wave.
    float p = v;
    #pragma unroll
    for (int d = 1; d < 64; d <<= 1) {
        float o = __shfl_up(p, d, 64);
        if (lane >= d) p *= o;
    }
    // Exclusive: shift right by one, lane 0 gets 1.
    float T = __shfl_up(p, 1, 64);
    if (lane == 0) T = 1.0f;

    const float w = alpha * T;
    const float tv = 2.0f + (float)lane * (4.0f / 63.0f);  // linspace(2,6,64)

    float cr = w * r;
    float cg = w * g;
    float cb = w * b;
    float cd = w * tv;

    // Wave-wide sum (butterfly) on 4 accumulators.
    #pragma unroll
    for (int d = 32; d > 0; d >>= 1) {
        cr += __shfl_down(cr, d, 64);
        cg += __shfl_down(cg, d, 64);
        cb += __shfl_down(cb, d, 64);
        cd += __shfl_down(cd, d, 64);
    }

    if (lane == 0) {
        float* o = rgb_map + (size_t)ray * 3;
        o[0] = cr;
        o[1] = cg;
        o[2] = cb;
        depth_map[ray] = cd;
    }
}

extern "C" void kernel_launch(void* const* d_in, const int* in_sizes, int n_in,
                              void* d_out, int out_size, void* d_ws, size_t ws_size,
                              hipStream_t stream) {
    const float* rgb   = (const float*)d_in[0];   // [B, 64, 3]
    const float* sigma = (const float*)d_in[1];   // [B, 64]
    const int n_rays = in_sizes[1] / NSAMP;

    float* rgb_map   = (float*)d_out;                        // first B*3 floats
    float* depth_map = (float*)d_out + (size_t)n_rays * 3;   // next B floats

    const int blocks = (n_rays + WAVES_PER_BLOCK - 1) / WAVES_PER_BLOCK;
    nerf_render_kernel<<<blocks, WAVES_PER_BLOCK * 64, 0, stream>>>(
        rgb, sigma, rgb_map, depth_map, n_rays);
}